// Round 11
// baseline (738.550 us; speedup 1.0000x reference)
//
#include <hip/hip_runtime.h>
#include <hip/hip_bf16.h>
#include <math.h>

#define B_CONST 256
#define T_CONST 8192
#define P_CONST 16
#define H_CONST 1024

typedef __bf16 bf16x8 __attribute__((ext_vector_type(8)));
typedef __bf16 bf16x4 __attribute__((ext_vector_type(4)));
typedef float  f32x4  __attribute__((ext_vector_type(4)));

typedef __attribute__((address_space(3))) void       as3_void;
typedef const __attribute__((address_space(1))) void as1_cvoid;

__device__ __forceinline__ void gload_lds16(const void* g, void* l) {
    __builtin_amdgcn_global_load_lds((as1_cvoid*)g, (as3_void*)l, 16, 0, 0);
}

// fast gelu: x * sigmoid(1.5957691 * x * (1 + 0.044715 x^2))
__device__ __forceinline__ float gelu_fast(float x) {
    float z = 1.5957691216057308f * x * __builtin_fmaf(0.044715f, x * x, 1.0f);
    return x * __builtin_amdgcn_rcpf(1.0f + __expf(-z));
}

// ------------- kernel 1: per-batch valid count via ballot binary search --------
// mask[b,t] = (t < length[b]) is a prefix mask, so valid = first zero.
__global__ __launch_bounds__(64) void k_valid(const float* __restrict__ x,
                                              int* __restrict__ valid) {
    const int b = blockIdx.x;
    const int l = threadIdx.x;
    const float* m = x + (size_t)b * (T_CONST * 2) + 1;   // mask[t] = m[2t]
    bool one1 = m[(size_t)2 * (l * 128)] > 0.5f;
    int c1 = __popcll(__ballot(one1));
    int v = 0;
    if (c1 > 0) {
        int base = (c1 - 1) * 128;
        bool one2 = m[(size_t)2 * (base + l * 2)] > 0.5f;
        int c2 = __popcll(__ballot(one2));          // >= 1
        int tp = base + 2 * c2 - 1;
        v = (m[(size_t)2 * tp] > 0.5f) ? (base + 2 * c2) : (base + 2 * c2 - 1);
    }
    if (l == 0) valid[b] = v;
}

// ------------- fused prep: scan (blk 0) + w1t (blk 1-4) + transposes -----------
// blk 5..1028: w2 -> w2t; blk 1029..2052: w3 -> w3t. One launch instead of 4.
__global__ __launch_bounds__(256) void k_prep(
    const int* __restrict__ valid, int* __restrict__ pc, int* __restrict__ starts,
    int* __restrict__ cum, float* __restrict__ out_pc,
    const float* __restrict__ w1, __bf16* __restrict__ w1t,
    const float* __restrict__ w2, __bf16* __restrict__ w2t,
    const float* __restrict__ w3, __bf16* __restrict__ w3t) {
    __shared__ int s[B_CONST];
    __shared__ float tile[32][33];
    const int bid = blockIdx.x;
    const int t = threadIdx.x;
    if (bid == 0) {
        int v = valid[t];
        int p = (v + P_CONST - 1) / P_CONST;
        s[t] = p;
        __syncthreads();
        for (int off = 1; off < B_CONST; off <<= 1) {
            int add = (t >= off) ? s[t - off] : 0;
            __syncthreads();
            s[t] += add;
            __syncthreads();
        }
        pc[t] = p;
        cum[t] = s[t];
        starts[t] = s[t] - p;
        out_pc[t] = (float)p;
    } else if (bid <= 4) {
        int n = (bid - 1) * 256 + t;
        for (int k = 0; k < 32; ++k)
            w1t[n * 32 + k] = (k < 16) ? (__bf16)w1[k * H_CONST + n] : (__bf16)0.f;
    } else {
        int fid = bid - 5;
        const float* W = w2; __bf16* WT = w2t;
        if (fid >= 1024) { W = w3; WT = w3t; fid -= 1024; }
        const int n0 = (fid & 31) * 32, k0 = (fid >> 5) * 32;
        const int c = t & 31, r0 = t >> 5;
        for (int r = r0; r < 32; r += 8)
            tile[r][c] = W[(size_t)(k0 + r) * H_CONST + n0 + c];
        __syncthreads();
        for (int r = r0; r < 32; r += 8)
            WT[(size_t)(n0 + r) * H_CONST + k0 + c] = (__bf16)tile[c][r];
    }
}

// ---------------- layer-1 fused gather+GEMM (K=32, R3 MFMA structure) ----------
__global__ __launch_bounds__(256) void k_l1_fused(
    const float* __restrict__ x, const int* __restrict__ valid,
    const int* __restrict__ cum, const int* __restrict__ starts,
    const __bf16* __restrict__ w1t, const float* __restrict__ bias,
    __bf16* __restrict__ C, int total) {
    __shared__ __bf16 As[128][32];
    __shared__ __bf16 Bs[128][32];

    const int lane = threadIdx.x & 63;
    const int wid  = threadIdx.x >> 6;
    const int wr = wid >> 1, wc = wid & 1;

    const int nwg_x = gridDim.x;
    const int orig = blockIdx.y * nwg_x + blockIdx.x;
    const int cpx = (nwg_x * gridDim.y) >> 3;
    const int wgid = (orig & 7) * cpx + (orig >> 3);
    const int brow = (wgid / nwg_x) * 128;
    const int bcol = (wgid % nwg_x) * 128;

    // stage B (w1t rows bcol..bcol+127, all 32 cols): 2 loads per wave
    const int sr = lane >> 2;
    const int sc = (lane & 3) * 8;
    const size_t b_base = (size_t)(bcol + wid * 16 + sr) * 32 + sc;
    gload_lds16(w1t + b_base,           &Bs[wid * 16][0]);
    gload_lds16(w1t + b_base + 64 * 32, &Bs[64 + wid * 16][0]);

    // compute A on the fly: thread t -> patch row t>>1, col-half t&1
    {
        const int r  = threadIdx.x >> 1;
        const int ch = threadIdx.x & 1;
        const int j  = brow + r;
        int lo = 0, hi = B_CONST - 1;
        while (lo < hi) { int mid = (lo + hi) >> 1; if (cum[mid] > j) hi = mid; else lo = mid + 1; }
        const int b = lo;
        const int p = j - starts[b];
        __bf16 vals[16];
        if (ch == 0) {
            const int vb = valid[b];
            const float* xb = x + (size_t)b * (T_CONST * 2) + 32 * p;
#pragma unroll
            for (int i = 0; i < 8; ++i) {
                float4 v = *(const float4*)(xb + 4 * i);
                int i0 = p * 16 + 2 * i;
                vals[2 * i]     = (__bf16)((i0 < vb)     ? v.x : 0.f);
                vals[2 * i + 1] = (__bf16)((i0 + 1 < vb) ? v.z : 0.f);
            }
        } else {
#pragma unroll
            for (int i = 0; i < 16; ++i) vals[i] = (__bf16)0.f;
        }
        *(bf16x8*)&As[r][ch * 16]     = *(bf16x8*)&vals[0];
        *(bf16x8*)&As[r][ch * 16 + 8] = *(bf16x8*)&vals[8];
    }
    __syncthreads();

    const int lr = lane & 15;
    const int lk = (lane >> 4) * 8;

    f32x4 acc[4][4];
#pragma unroll
    for (int i = 0; i < 4; ++i)
#pragma unroll
        for (int j = 0; j < 4; ++j)
            acc[i][j] = (f32x4){0.f, 0.f, 0.f, 0.f};

    bf16x8 af[4], bfr[4];
#pragma unroll
    for (int mf = 0; mf < 4; ++mf)
        af[mf] = *(const bf16x8*)&As[wr * 64 + mf * 16 + lr][lk];
#pragma unroll
    for (int nf = 0; nf < 4; ++nf)
        bfr[nf] = *(const bf16x8*)&Bs[wc * 64 + nf * 16 + lr][lk];
#pragma unroll
    for (int mf = 0; mf < 4; ++mf)
#pragma unroll
        for (int nf = 0; nf < 4; ++nf)
            acc[mf][nf] = __builtin_amdgcn_mfma_f32_16x16x32_bf16(
                bfr[nf], af[mf], acc[mf][nf], 0, 0, 0);

    const int c4 = (lane >> 4) << 2;
#pragma unroll
    for (int nf = 0; nf < 4; ++nf) {
        const int col0 = bcol + wc * 64 + nf * 16 + c4;
        const f32x4 bv = *(const f32x4*)&bias[col0];
#pragma unroll
        for (int mf = 0; mf < 4; ++mf) {
            const int row = brow + wr * 64 + mf * 16 + lr;
            f32x4 v = acc[mf][nf] + bv;
#pragma unroll
            for (int rr = 0; rr < 4; ++rr) v[rr] = gelu_fast(v[rr]);
            bf16x4 o;
#pragma unroll
            for (int rr = 0; rr < 4; ++rr) o[rr] = (__bf16)v[rr];
            *(bf16x4*)&C[(size_t)row * H_CONST + col0] = o;
        }
    }
}

// ---------------- big GEMM: single-buffer BK=64, reg-fragment pipelining -------
// R6 proven schedule; ONLY change: __launch_bounds__(256, 4) -> 4 blocks/CU
// (LDS 4x32=128KB <= 160, VGPR 80 <= 128). Session dose-response 1/2/3 blocks
// = 141/114/86 us; cross-block overlap hides the sync1 vmcnt-drain stall.
// Grid 2056 = 2.0 rounds of 1024 co-resident (vs 2.68 ragged at 768).
template <bool GELU, typename TOut>
__global__ __launch_bounds__(256, 4) void k_gemm_sb(
    const __bf16* __restrict__ A, const __bf16* __restrict__ WT,
    const float* __restrict__ bias, TOut* __restrict__ C,
    int M, int N, int K) {
    __shared__ __bf16 As[128][64];   // 16 KiB
    __shared__ __bf16 Bs[128][64];   // 16 KiB

    const int lane = threadIdx.x & 63;
    const int wid  = threadIdx.x >> 6;
    const int wr = wid >> 1, wc = wid & 1;

    const int nwg_x = gridDim.x;
    const int orig = blockIdx.y * nwg_x + blockIdx.x;
    const int cpx = (nwg_x * gridDim.y) >> 3;   // nwg = 2056, %8 == 0
    const int wgid = (orig & 7) * cpx + (orig >> 3);
    const int brow = (wgid / nwg_x) * 128;
    const int bcol = (wgid % nwg_x) * 128;

    f32x4 acc[4][4];
#pragma unroll
    for (int i = 0; i < 4; ++i)
#pragma unroll
        for (int j = 0; j < 4; ++j)
            acc[i][j] = (f32x4){0.f, 0.f, 0.f, 0.f};

    // staging: per wave 32 rows of A + 32 rows of B per K-tile, 8-row chunks.
    // global source pre-swizzled: LDS[row][8j..8j+7] = global col-group j^(row&7).
    const int lr8 = lane >> 3;                       // 0..7
    const int swz = 8 * ((lane & 7) ^ lr8);
    const __bf16* Ab = A  + (size_t)(brow + wid * 32 + lr8) * K + swz;
    const __bf16* Bb = WT + (size_t)(bcol + wid * 32 + lr8) * K + swz;
    const size_t rs8 = (size_t)8 * K;

#define STG(kt)                                                        \
    do {                                                               \
        gload_lds16(Ab + (kt),           &As[wid * 32][0]);            \
        gload_lds16(Ab + rs8 + (kt),     &As[wid * 32 + 8][0]);        \
        gload_lds16(Ab + 2 * rs8 + (kt), &As[wid * 32 + 16][0]);       \
        gload_lds16(Ab + 3 * rs8 + (kt), &As[wid * 32 + 24][0]);       \
        gload_lds16(Bb + (kt),           &Bs[wid * 32][0]);            \
        gload_lds16(Bb + rs8 + (kt),     &Bs[wid * 32 + 8][0]);        \
        gload_lds16(Bb + 2 * rs8 + (kt), &Bs[wid * 32 + 16][0]);       \
        gload_lds16(Bb + 3 * rs8 + (kt), &Bs[wid * 32 + 24][0]);       \
    } while (0)

    // fragment-read addressing (swizzled)
    const int lr   = lane & 15;
    const int hi16 = (lane >> 4) * 16;
    const int rswz = (lane & 7) << 4;

    const int nt = K >> 6;
    STG(0);

    for (int t = 0; t < nt; ++t) {
        __syncthreads();                 // stage-t loads landed (vmcnt drain)

        const char* ab = (const char*)&As[0][0];
        const char* bb = (const char*)&Bs[0][0];
        bf16x8 af[2][4], bfr[2][4];
#pragma unroll
        for (int kk = 0; kk < 2; ++kk) {
            const int cb = (kk * 64 + hi16) ^ rswz;
#pragma unroll
            for (int mf = 0; mf < 4; ++mf)
                af[kk][mf] = *(const bf16x8*)(ab + (wr * 64 + mf * 16 + lr) * 128 + cb);
#pragma unroll
            for (int nf = 0; nf < 4; ++nf)
                bfr[kk][nf] = *(const bf16x8*)(bb + (wc * 64 + nf * 16 + lr) * 128 + cb);
        }
        __syncthreads();                 // all waves done reading LDS (cheap)

        if (t + 1 < nt) STG((t + 1) << 6);   // next tile flies under the MFMAs

        __builtin_amdgcn_s_setprio(1);
#pragma unroll
        for (int kk = 0; kk < 2; ++kk)
#pragma unroll
            for (int mf = 0; mf < 4; ++mf)
#pragma unroll
                for (int nf = 0; nf < 4; ++nf)
                    acc[mf][nf] = __builtin_amdgcn_mfma_f32_16x16x32_bf16(
                        bfr[kk][nf], af[kk][mf], acc[mf][nf], 0, 0, 0);
        __builtin_amdgcn_s_setprio(0);
    }
#undef STG

    // epilogue: swapped C^T frag -> lane holds 4 consecutive cols of one row
    const int c4 = (lane >> 4) << 2;
#pragma unroll
    for (int nf = 0; nf < 4; ++nf) {
        const int col0 = bcol + wc * 64 + nf * 16 + c4;
        const f32x4 bv = *(const f32x4*)&bias[col0];
#pragma unroll
        for (int mf = 0; mf < 4; ++mf) {
            const int row = brow + wr * 64 + mf * 16 + lr;
            f32x4 v = acc[mf][nf] + bv;
            if (GELU) {
#pragma unroll
                for (int rr = 0; rr < 4; ++rr) v[rr] = gelu_fast(v[rr]);
            }
            if constexpr (sizeof(TOut) == 4) {
                *(f32x4*)&C[(size_t)row * N + col0] = v;
            } else {
                bf16x4 o;
#pragma unroll
                for (int rr = 0; rr < 4; ++rr) o[rr] = (__bf16)v[rr];
                *(bf16x4*)&C[(size_t)row * N + col0] = o;
            }
        }
    }
}

extern "C" void kernel_launch(void* const* d_in, const int* in_sizes, int n_in,
                              void* d_out, int out_size, void* d_ws, size_t ws_size,
                              hipStream_t stream) {
    const float* x  = (const float*)d_in[0];
    const float* w1 = (const float*)d_in[1];
    const float* b1 = (const float*)d_in[2];
    const float* w2 = (const float*)d_in[3];
    const float* b2 = (const float*)d_in[4];
    const float* w3 = (const float*)d_in[5];
    const float* b3 = (const float*)d_in[6];

    const int total = (out_size - B_CONST) / H_CONST;  // 32896
    float* out = (float*)d_out;
    float* out_pc = out + (size_t)total * H_CONST;

    char* ws = (char*)d_ws;
    int* valid  = (int*)ws;
    int* pc     = valid + 256;
    int* starts = pc + 256;
    int* cum    = starts + 256;
    __bf16* w1t = (__bf16*)(ws + 4096);                        // 1024x32
    __bf16* w2t = w1t + (size_t)H_CONST * 32;                  // 1024x1024
    __bf16* w3t = w2t + (size_t)H_CONST * H_CONST;             // 1024x1024
    __bf16* h1 = w3t + (size_t)H_CONST * H_CONST;              // total x 1024
    __bf16* h2 = h1 + (size_t)total * H_CONST;                 // total x 1024

    k_valid<<<B_CONST, 64, 0, stream>>>(x, valid);
    k_prep<<<2053, 256, 0, stream>>>(valid, pc, starts, cum, out_pc,
                                     w1, w1t, w2, w2t, w3, w3t);

    // layer 1: fused gather + K=32 GEMM
    dim3 g1(H_CONST / 128, total / 128);   // 8 x 257 = 2056, %8 == 0
    k_l1_fused<<<g1, dim3(256), 0, stream>>>(x, valid, cum, starts, w1t, b1, h1, total);

    // layers 2/3: R6 single-buffer BK=64 kernel at 4 blocks/CU
    k_gemm_sb<true,  __bf16><<<g1, dim3(256), 0, stream>>>(h1, w2t, b2, h2, total, H_CONST, H_CONST);
    k_gemm_sb<false, float ><<<g1, dim3(256), 0, stream>>>(h2, w3t, b3, out, total, H_CONST, H_CONST);
}

// Round 12
// 144.823 us; speedup vs baseline: 5.0997x; 5.0997x over previous
//
#include <hip/hip_runtime.h>
#include <hip/hip_bf16.h>
#include <hip/hip_fp8.h>
#include <math.h>

#define B_CONST 256
#define T_CONST 8192
#define P_CONST 16
#define H_CONST 1024

typedef __bf16 bf16x8 __attribute__((ext_vector_type(8)));
typedef __bf16 bf16x4 __attribute__((ext_vector_type(4)));
typedef float  f32x4  __attribute__((ext_vector_type(4)));
typedef int    i32x4  __attribute__((ext_vector_type(4)));
typedef int    i32x8  __attribute__((ext_vector_type(8)));

typedef __attribute__((address_space(3))) void       as3_void;
typedef const __attribute__((address_space(1))) void as1_cvoid;

__device__ __forceinline__ void gload_lds16(const void* g, void* l) {
    __builtin_amdgcn_global_load_lds((as1_cvoid*)g, (as3_void*)l, 16, 0, 0);
}

// fast gelu: x * sigmoid(1.5957691 * x * (1 + 0.044715 x^2))
__device__ __forceinline__ float gelu_fast(float x) {
    float z = 1.5957691216057308f * x * __builtin_fmaf(0.044715f, x * x, 1.0f);
    return x * __builtin_amdgcn_rcpf(1.0f + __expf(-z));
}

__device__ __forceinline__ unsigned char f2fp8(float v) {
    __hip_fp8_e4m3 q(v);
    return (unsigned char)q.__x;
}
__device__ __forceinline__ unsigned int pack_fp8x4(f32x4 v) {
    return (unsigned)f2fp8(v[0]) | ((unsigned)f2fp8(v[1]) << 8) |
           ((unsigned)f2fp8(v[2]) << 16) | ((unsigned)f2fp8(v[3]) << 24);
}

// E8M0 scales, replicated in all 4 bytes (op_sel=0 -> byte 0)
#define SC_UNIT 0x7F7F7F7F   // 2^0
#define SC_W32  0x7A7A7A7A   // 2^-5 (weights pre-scaled x32 at prep)

// ------------- kernel 1: per-batch valid count via ballot binary search --------
__global__ __launch_bounds__(64) void k_valid(const float* __restrict__ x,
                                              int* __restrict__ valid) {
    const int b = blockIdx.x;
    const int l = threadIdx.x;
    const float* m = x + (size_t)b * (T_CONST * 2) + 1;   // mask[t] = m[2t]
    bool one1 = m[(size_t)2 * (l * 128)] > 0.5f;
    int c1 = __popcll(__ballot(one1));
    int v = 0;
    if (c1 > 0) {
        int base = (c1 - 1) * 128;
        bool one2 = m[(size_t)2 * (base + l * 2)] > 0.5f;
        int c2 = __popcll(__ballot(one2));          // >= 1
        int tp = base + 2 * c2 - 1;
        v = (m[(size_t)2 * tp] > 0.5f) ? (base + 2 * c2) : (base + 2 * c2 - 1);
    }
    if (l == 0) valid[b] = v;
}

// ------------- fused prep: scan (blk 0) + w1t bf16 (blk 1-4) + fp8 transposes --
// blk 5..1028: w2 -> w2t fp8 (x32); blk 1029..2052: w3 -> w3t fp8 (x32).
__global__ __launch_bounds__(256) void k_prep(
    const int* __restrict__ valid, int* __restrict__ pc, int* __restrict__ starts,
    int* __restrict__ cum, float* __restrict__ out_pc,
    const float* __restrict__ w1, __bf16* __restrict__ w1t,
    const float* __restrict__ w2, unsigned char* __restrict__ w2t,
    const float* __restrict__ w3, unsigned char* __restrict__ w3t) {
    __shared__ int s[B_CONST];
    __shared__ float tile[32][33];
    const int bid = blockIdx.x;
    const int t = threadIdx.x;
    if (bid == 0) {
        int v = valid[t];
        int p = (v + P_CONST - 1) / P_CONST;
        s[t] = p;
        __syncthreads();
        for (int off = 1; off < B_CONST; off <<= 1) {
            int add = (t >= off) ? s[t - off] : 0;
            __syncthreads();
            s[t] += add;
            __syncthreads();
        }
        pc[t] = p;
        cum[t] = s[t];
        starts[t] = s[t] - p;
        out_pc[t] = (float)p;
    } else if (bid <= 4) {
        int n = (bid - 1) * 256 + t;
        for (int k = 0; k < 32; ++k)
            w1t[n * 32 + k] = (k < 16) ? (__bf16)w1[k * H_CONST + n] : (__bf16)0.f;
    } else {
        int fid = bid - 5;
        const float* W = w2; unsigned char* WT = w2t;
        if (fid >= 1024) { W = w3; WT = w3t; fid -= 1024; }
        const int n0 = (fid & 31) * 32, k0 = (fid >> 5) * 32;
        const int c = t & 31, r0 = t >> 5;
        for (int r = r0; r < 32; r += 8)
            tile[r][c] = W[(size_t)(k0 + r) * H_CONST + n0 + c];
        __syncthreads();
        for (int r = r0; r < 32; r += 8)
            WT[(size_t)(n0 + r) * H_CONST + k0 + c] = f2fp8(32.f * tile[c][r]);
    }
}

// ---------------- layer-1 fused gather+GEMM (K=32 bf16), fp8 output ------------
__global__ __launch_bounds__(256) void k_l1_fused(
    const float* __restrict__ x, const int* __restrict__ valid,
    const int* __restrict__ cum, const int* __restrict__ starts,
    const __bf16* __restrict__ w1t, const float* __restrict__ bias,
    unsigned char* __restrict__ C, int total) {
    __shared__ __bf16 As[128][32];
    __shared__ __bf16 Bs[128][32];

    const int lane = threadIdx.x & 63;
    const int wid  = threadIdx.x >> 6;
    const int wr = wid >> 1, wc = wid & 1;

    const int nwg_x = gridDim.x;
    const int orig = blockIdx.y * nwg_x + blockIdx.x;
    const int cpx = (nwg_x * gridDim.y) >> 3;
    const int wgid = (orig & 7) * cpx + (orig >> 3);
    const int brow = (wgid / nwg_x) * 128;
    const int bcol = (wgid % nwg_x) * 128;

    const int sr = lane >> 2;
    const int sc = (lane & 3) * 8;
    const size_t b_base = (size_t)(bcol + wid * 16 + sr) * 32 + sc;
    gload_lds16(w1t + b_base,           &Bs[wid * 16][0]);
    gload_lds16(w1t + b_base + 64 * 32, &Bs[64 + wid * 16][0]);

    {
        const int r  = threadIdx.x >> 1;
        const int ch = threadIdx.x & 1;
        const int j  = brow + r;
        int lo = 0, hi = B_CONST - 1;
        while (lo < hi) { int mid = (lo + hi) >> 1; if (cum[mid] > j) hi = mid; else lo = mid + 1; }
        const int b = lo;
        const int p = j - starts[b];
        __bf16 vals[16];
        if (ch == 0) {
            const int vb = valid[b];
            const float* xb = x + (size_t)b * (T_CONST * 2) + 32 * p;
#pragma unroll
            for (int i = 0; i < 8; ++i) {
                float4 v = *(const float4*)(xb + 4 * i);
                int i0 = p * 16 + 2 * i;
                vals[2 * i]     = (__bf16)((i0 < vb)     ? v.x : 0.f);
                vals[2 * i + 1] = (__bf16)((i0 + 1 < vb) ? v.z : 0.f);
            }
        } else {
#pragma unroll
            for (int i = 0; i < 16; ++i) vals[i] = (__bf16)0.f;
        }
        *(bf16x8*)&As[r][ch * 16]     = *(bf16x8*)&vals[0];
        *(bf16x8*)&As[r][ch * 16 + 8] = *(bf16x8*)&vals[8];
    }
    __syncthreads();

    const int lr = lane & 15;
    const int lk = (lane >> 4) * 8;

    f32x4 acc[4][4];
#pragma unroll
    for (int i = 0; i < 4; ++i)
#pragma unroll
        for (int j = 0; j < 4; ++j)
            acc[i][j] = (f32x4){0.f, 0.f, 0.f, 0.f};

    bf16x8 af[4], bfr[4];
#pragma unroll
    for (int mf = 0; mf < 4; ++mf)
        af[mf] = *(const bf16x8*)&As[wr * 64 + mf * 16 + lr][lk];
#pragma unroll
    for (int nf = 0; nf < 4; ++nf)
        bfr[nf] = *(const bf16x8*)&Bs[wc * 64 + nf * 16 + lr][lk];
#pragma unroll
    for (int mf = 0; mf < 4; ++mf)
#pragma unroll
        for (int nf = 0; nf < 4; ++nf)
            acc[mf][nf] = __builtin_amdgcn_mfma_f32_16x16x32_bf16(
                bfr[nf], af[mf], acc[mf][nf], 0, 0, 0);

    const int c4 = (lane >> 4) << 2;
#pragma unroll
    for (int nf = 0; nf < 4; ++nf) {
        const int col0 = bcol + wc * 64 + nf * 16 + c4;
        const f32x4 bv = *(const f32x4*)&bias[col0];
#pragma unroll
        for (int mf = 0; mf < 4; ++mf) {
            const int row = brow + wr * 64 + mf * 16 + lr;
            f32x4 v = acc[mf][nf] + bv;
#pragma unroll
            for (int rr = 0; rr < 4; ++rr) v[rr] = gelu_fast(v[rr]);
            *(unsigned int*)&C[(size_t)row * H_CONST + col0] = pack_fp8x4(v);
        }
    }
}

// ---------------- big GEMM: R6 schedule, MX-fp8 K=128 (m148 port) --------------
// 128x128 tile, 4 waves 2x2, BK=128 (fp8 -> same 128-B rows / 32 KiB LDS /
// 3 blocks/CU as the proven bf16 kernel; staging bytes identical, nt=8).
// Same 2-barrier loop, same XOR swizzle (byte-level identical -> 0 conflicts).
// mfma_scale_f32_16x16x128_f8f6f4, fmt fp8/fp8; weights carry E8M0 scale 2^-5
// (pre-scaled x32 at prep), activations scale 1.0.
template <bool GELU, typename TOut>
__global__ __launch_bounds__(256, 3) void k_gemm_mx(
    const unsigned char* __restrict__ A, const unsigned char* __restrict__ WT,
    const float* __restrict__ bias, TOut* __restrict__ C,
    int M, int N, int K) {
    __shared__ unsigned char As[128][128];   // 16 KiB
    __shared__ unsigned char Bs[128][128];   // 16 KiB

    const int lane = threadIdx.x & 63;
    const int wid  = threadIdx.x >> 6;
    const int wr = wid >> 1, wc = wid & 1;

    const int nwg_x = gridDim.x;
    const int orig = blockIdx.y * nwg_x + blockIdx.x;
    const int cpx = (nwg_x * gridDim.y) >> 3;   // nwg = 2056, %8 == 0
    const int wgid = (orig & 7) * cpx + (orig >> 3);
    const int brow = (wgid / nwg_x) * 128;
    const int bcol = (wgid % nwg_x) * 128;

    f32x4 acc[4][4];
#pragma unroll
    for (int i = 0; i < 4; ++i)
#pragma unroll
        for (int j = 0; j < 4; ++j)
            acc[i][j] = (f32x4){0.f, 0.f, 0.f, 0.f};

    // staging: per wave 32 rows of A + 32 rows of B per K-tile, 8-row chunks,
    // 128-B rows = 8 x 16B slots. Pre-swizzled global source: LDS[row][slot]
    // holds global slot ^ (row&7).  (byte-identical to the proven bf16 kernel)
    const int lr8  = lane >> 3;                      // 0..7
    const int swzB = 16 * ((lane & 7) ^ lr8);        // byte offset in 128B row
    const unsigned char* Ab = A  + (size_t)(brow + wid * 32 + lr8) * K + swzB;
    const unsigned char* Bb = WT + (size_t)(bcol + wid * 32 + lr8) * K + swzB;
    const size_t rs8 = (size_t)8 * K;

#define STG(kt)                                                        \
    do {                                                               \
        gload_lds16(Ab + (kt),           &As[wid * 32][0]);            \
        gload_lds16(Ab + rs8 + (kt),     &As[wid * 32 + 8][0]);        \
        gload_lds16(Ab + 2 * rs8 + (kt), &As[wid * 32 + 16][0]);       \
        gload_lds16(Ab + 3 * rs8 + (kt), &As[wid * 32 + 24][0]);       \
        gload_lds16(Bb + (kt),           &Bs[wid * 32][0]);            \
        gload_lds16(Bb + rs8 + (kt),     &Bs[wid * 32 + 8][0]);        \
        gload_lds16(Bb + 2 * rs8 + (kt), &Bs[wid * 32 + 16][0]);       \
        gload_lds16(Bb + 3 * rs8 + (kt), &Bs[wid * 32 + 24][0]);       \
    } while (0)

    // fragment reads: lane supplies op-row (l&15 within frag), k-bytes
    // (l>>4)*32 .. +31 = slots {2g, 2g+1}, each XOR-swizzled with row&7.
    const int lr = lane & 15;
    const int rs = lr & 7;
    const int g2 = (lane >> 4) * 2;
    const int s_lo = (g2 ^ rs) << 4;
    const int s_hi = ((g2 + 1) ^ rs) << 4;

    const int nt = K >> 7;   // 8 K-tiles of 128
    STG(0);

    for (int t = 0; t < nt; ++t) {
        __syncthreads();                 // stage-t loads landed (vmcnt drain)

        const char* ab = (const char*)&As[0][0];
        const char* bb = (const char*)&Bs[0][0];
        i32x8 af[4], bfr[4];
#pragma unroll
        for (int mf = 0; mf < 4; ++mf) {
            const int rb = (wr * 64 + mf * 16 + lr) * 128;
            i32x4 lo = *(const i32x4*)(ab + rb + s_lo);
            i32x4 hi = *(const i32x4*)(ab + rb + s_hi);
            af[mf] = __builtin_shufflevector(lo, hi, 0, 1, 2, 3, 4, 5, 6, 7);
        }
#pragma unroll
        for (int nf = 0; nf < 4; ++nf) {
            const int rb = (wc * 64 + nf * 16 + lr) * 128;
            i32x4 lo = *(const i32x4*)(bb + rb + s_lo);
            i32x4 hi = *(const i32x4*)(bb + rb + s_hi);
            bfr[nf] = __builtin_shufflevector(lo, hi, 0, 1, 2, 3, 4, 5, 6, 7);
        }
        __syncthreads();                 // all waves done reading LDS (cheap)

        if (t + 1 < nt) STG((t + 1) << 7);   // next tile flies under the MFMAs

        __builtin_amdgcn_s_setprio(1);
#pragma unroll
        for (int mf = 0; mf < 4; ++mf)
#pragma unroll
            for (int nf = 0; nf < 4; ++nf)
                acc[mf][nf] = __builtin_amdgcn_mfma_scale_f32_16x16x128_f8f6f4(
                    bfr[nf], af[mf], acc[mf][nf],
                    0, 0,              // cbsz, blgp: fp8 / fp8
                    0, SC_W32,         // op_sel_a, scale_a (weights, x32 undone)
                    0, SC_UNIT);       // op_sel_b, scale_b (activations)
        __builtin_amdgcn_s_setprio(0);
    }
#undef STG

    // epilogue: swapped C^T frag -> lane holds 4 consecutive cols of one row
    const int c4 = (lane >> 4) << 2;
#pragma unroll
    for (int nf = 0; nf < 4; ++nf) {
        const int col0 = bcol + wc * 64 + nf * 16 + c4;
        const f32x4 bv = *(const f32x4*)&bias[col0];
#pragma unroll
        for (int mf = 0; mf < 4; ++mf) {
            const int row = brow + wr * 64 + mf * 16 + lr;
            f32x4 v = acc[mf][nf] + bv;
            if (GELU) {
#pragma unroll
                for (int rr = 0; rr < 4; ++rr) v[rr] = gelu_fast(v[rr]);
            }
            if constexpr (sizeof(TOut) == 4) {
                *(f32x4*)&C[(size_t)row * N + col0] = v;
            } else {
                *(unsigned int*)&C[(size_t)row * N + col0] = pack_fp8x4(v);
            }
        }
    }
}

extern "C" void kernel_launch(void* const* d_in, const int* in_sizes, int n_in,
                              void* d_out, int out_size, void* d_ws, size_t ws_size,
                              hipStream_t stream) {
    const float* x  = (const float*)d_in[0];
    const float* w1 = (const float*)d_in[1];
    const float* b1 = (const float*)d_in[2];
    const float* w2 = (const float*)d_in[3];
    const float* b2 = (const float*)d_in[4];
    const float* w3 = (const float*)d_in[5];
    const float* b3 = (const float*)d_in[6];

    const int total = (out_size - B_CONST) / H_CONST;  // 32896
    float* out = (float*)d_out;
    float* out_pc = out + (size_t)total * H_CONST;

    char* ws = (char*)d_ws;
    int* valid  = (int*)ws;
    int* pc     = valid + 256;
    int* starts = pc + 256;
    int* cum    = starts + 256;
    __bf16* w1t = (__bf16*)(ws + 4096);                            // 1024x32 bf16
    unsigned char* w2t = (unsigned char*)(w1t + (size_t)H_CONST * 32);  // 1MB fp8
    unsigned char* w3t = w2t + (size_t)H_CONST * H_CONST;               // 1MB fp8
    unsigned char* h1  = w3t + (size_t)H_CONST * H_CONST;          // total x 1024 fp8
    unsigned char* h2  = h1 + (size_t)total * H_CONST;             // total x 1024 fp8

    k_valid<<<B_CONST, 64, 0, stream>>>(x, valid);
    k_prep<<<2053, 256, 0, stream>>>(valid, pc, starts, cum, out_pc,
                                     w1, w1t, w2, w2t, w3, w3t);

    // layer 1: fused gather + K=32 bf16 GEMM, fp8 output
    dim3 g1(H_CONST / 128, total / 128);   // 8 x 257 = 2056, %8 == 0
    k_l1_fused<<<g1, dim3(256), 0, stream>>>(x, valid, cum, starts, w1t, b1, h1, total);

    // layers 2/3: MX-fp8 K=128 kernel (R6 schedule), 3 blocks/CU
    k_gemm_mx<true,  unsigned char><<<g1, dim3(256), 0, stream>>>(h1, w2t, b2, h2, total, H_CONST, H_CONST);
    k_gemm_mx<false, float        ><<<g1, dim3(256), 0, stream>>>(h2, w3t, b3, out, total, H_CONST, H_CONST);
}

// Round 13
// 142.234 us; speedup vs baseline: 5.1925x; 1.0182x over previous
//
#include <hip/hip_runtime.h>
#include <hip/hip_bf16.h>
#include <math.h>

#define B_CONST 256
#define T_CONST 8192
#define P_CONST 16
#define H_CONST 1024

typedef __bf16 bf16x8 __attribute__((ext_vector_type(8)));
typedef __bf16 bf16x4 __attribute__((ext_vector_type(4)));
typedef float  f32x4  __attribute__((ext_vector_type(4)));
typedef int    i32x4  __attribute__((ext_vector_type(4)));
typedef int    i32x8  __attribute__((ext_vector_type(8)));

typedef __attribute__((address_space(3))) void       as3_void;
typedef const __attribute__((address_space(1))) void as1_cvoid;

__device__ __forceinline__ void gload_lds16(const void* g, void* l) {
    __builtin_amdgcn_global_load_lds((as1_cvoid*)g, (as3_void*)l, 16, 0, 0);
}

// fast gelu: x * sigmoid(1.5957691 * x * (1 + 0.044715 x^2))
__device__ __forceinline__ float gelu_fast(float x) {
    float z = 1.5957691216057308f * x * __builtin_fmaf(0.044715f, x * x, 1.0f);
    return x * __builtin_amdgcn_rcpf(1.0f + __expf(-z));
}

// fp4 e2m1 quantize (round to nearest of {0,.5,1,1.5,2,3,4,6}, sign bit 3)
__device__ __forceinline__ unsigned int f2fp4(float v) {
    float a = __builtin_fabsf(v);
    unsigned s = (__builtin_bit_cast(unsigned int, v) >> 31) << 3;
    unsigned c = (a < 0.25f) ? 0u : (a < 0.75f) ? 1u : (a < 1.25f) ? 2u :
                 (a < 1.75f) ? 3u : (a < 2.5f)  ? 4u : (a < 3.5f)  ? 5u :
                 (a < 5.0f)  ? 6u : 7u;
    return s | c;
}
__device__ __forceinline__ unsigned short pack_fp4x4(f32x4 v) {
    return (unsigned short)(f2fp4(v[0]) | (f2fp4(v[1]) << 4) |
                            (f2fp4(v[2]) << 8) | (f2fp4(v[3]) << 12));
}

// E8M0 scales, replicated bytes (op_sel=0 -> byte 0)
#define SC_UNIT 0x7F7F7F7F   // 2^0
#define SC_W32  0x7A7A7A7A   // 2^-5 (weights pre-scaled x32 at prep)

// ------------- kernel 1: per-batch valid count via ballot binary search --------
__global__ __launch_bounds__(64) void k_valid(const float* __restrict__ x,
                                              int* __restrict__ valid) {
    const int b = blockIdx.x;
    const int l = threadIdx.x;
    const float* m = x + (size_t)b * (T_CONST * 2) + 1;   // mask[t] = m[2t]
    bool one1 = m[(size_t)2 * (l * 128)] > 0.5f;
    int c1 = __popcll(__ballot(one1));
    int v = 0;
    if (c1 > 0) {
        int base = (c1 - 1) * 128;
        bool one2 = m[(size_t)2 * (base + l * 2)] > 0.5f;
        int c2 = __popcll(__ballot(one2));          // >= 1
        int tp = base + 2 * c2 - 1;
        v = (m[(size_t)2 * tp] > 0.5f) ? (base + 2 * c2) : (base + 2 * c2 - 1);
    }
    if (l == 0) valid[b] = v;
}

// ------------- fused prep: scan (blk 0) + w1t bf16 (blk 1-4) + fp4 transposes --
// blk 5..1028: w2 -> w2t fp4 (x32, packed 2/byte); blk 1029..2052: w3 -> w3t.
__global__ __launch_bounds__(256) void k_prep(
    const int* __restrict__ valid, int* __restrict__ pc, int* __restrict__ starts,
    int* __restrict__ cum, float* __restrict__ out_pc,
    const float* __restrict__ w1, __bf16* __restrict__ w1t,
    const float* __restrict__ w2, unsigned char* __restrict__ w2t,
    const float* __restrict__ w3, unsigned char* __restrict__ w3t) {
    __shared__ int s[B_CONST];
    __shared__ float tile[32][33];
    const int bid = blockIdx.x;
    const int t = threadIdx.x;
    if (bid == 0) {
        int v = valid[t];
        int p = (v + P_CONST - 1) / P_CONST;
        s[t] = p;
        __syncthreads();
        for (int off = 1; off < B_CONST; off <<= 1) {
            int add = (t >= off) ? s[t - off] : 0;
            __syncthreads();
            s[t] += add;
            __syncthreads();
        }
        pc[t] = p;
        cum[t] = s[t];
        starts[t] = s[t] - p;
        out_pc[t] = (float)p;
    } else if (bid <= 4) {
        int n = (bid - 1) * 256 + t;
        for (int k = 0; k < 32; ++k)
            w1t[n * 32 + k] = (k < 16) ? (__bf16)w1[k * H_CONST + n] : (__bf16)0.f;
    } else {
        int fid = bid - 5;
        const float* W = w2; unsigned char* WT = w2t;
        if (fid >= 1024) { W = w3; WT = w3t; fid -= 1024; }
        const int n0 = (fid & 31) * 32, k0 = (fid >> 5) * 32;
        const int c = t & 31, r0 = t >> 5;
        for (int r = r0; r < 32; r += 8)
            tile[r][c] = W[(size_t)(k0 + r) * H_CONST + n0 + c];
        __syncthreads();
        // write fp4-packed transposed: row n (32) x 16 bytes (32 k / 2)
        const int nl = t >> 3;          // 0..31
        const int b0 = t & 7;           // handles bytes b0 and b0+8
        unsigned char* dst = WT + (size_t)(n0 + nl) * (H_CONST / 2) + (k0 >> 1);
#pragma unroll
        for (int h = 0; h < 2; ++h) {
            int b = b0 + h * 8;
            unsigned lo = f2fp4(32.f * tile[2 * b][nl]);
            unsigned hi = f2fp4(32.f * tile[2 * b + 1][nl]);
            dst[b] = (unsigned char)(lo | (hi << 4));
        }
    }
}

// ---------------- layer-1 fused gather+GEMM (K=32 bf16), fp4 output ------------
__global__ __launch_bounds__(256) void k_l1_fused(
    const float* __restrict__ x, const int* __restrict__ valid,
    const int* __restrict__ cum, const int* __restrict__ starts,
    const __bf16* __restrict__ w1t, const float* __restrict__ bias,
    unsigned char* __restrict__ C, int total) {
    __shared__ __bf16 As[128][32];
    __shared__ __bf16 Bs[128][32];

    const int lane = threadIdx.x & 63;
    const int wid  = threadIdx.x >> 6;
    const int wr = wid >> 1, wc = wid & 1;

    const int nwg_x = gridDim.x;
    const int orig = blockIdx.y * nwg_x + blockIdx.x;
    const int cpx = (nwg_x * gridDim.y) >> 3;
    const int wgid = (orig & 7) * cpx + (orig >> 3);
    const int brow = (wgid / nwg_x) * 128;
    const int bcol = (wgid % nwg_x) * 128;

    const int sr = lane >> 2;
    const int sc = (lane & 3) * 8;
    const size_t b_base = (size_t)(bcol + wid * 16 + sr) * 32 + sc;
    gload_lds16(w1t + b_base,           &Bs[wid * 16][0]);
    gload_lds16(w1t + b_base + 64 * 32, &Bs[64 + wid * 16][0]);

    {
        const int r  = threadIdx.x >> 1;
        const int ch = threadIdx.x & 1;
        const int j  = brow + r;
        int lo = 0, hi = B_CONST - 1;
        while (lo < hi) { int mid = (lo + hi) >> 1; if (cum[mid] > j) hi = mid; else lo = mid + 1; }
        const int b = lo;
        const int p = j - starts[b];
        __bf16 vals[16];
        if (ch == 0) {
            const int vb = valid[b];
            const float* xb = x + (size_t)b * (T_CONST * 2) + 32 * p;
#pragma unroll
            for (int i = 0; i < 8; ++i) {
                float4 v = *(const float4*)(xb + 4 * i);
                int i0 = p * 16 + 2 * i;
                vals[2 * i]     = (__bf16)((i0 < vb)     ? v.x : 0.f);
                vals[2 * i + 1] = (__bf16)((i0 + 1 < vb) ? v.z : 0.f);
            }
        } else {
#pragma unroll
            for (int i = 0; i < 16; ++i) vals[i] = (__bf16)0.f;
        }
        *(bf16x8*)&As[r][ch * 16]     = *(bf16x8*)&vals[0];
        *(bf16x8*)&As[r][ch * 16 + 8] = *(bf16x8*)&vals[8];
    }
    __syncthreads();

    const int lr = lane & 15;
    const int lk = (lane >> 4) * 8;

    f32x4 acc[4][4];
#pragma unroll
    for (int i = 0; i < 4; ++i)
#pragma unroll
        for (int j = 0; j < 4; ++j)
            acc[i][j] = (f32x4){0.f, 0.f, 0.f, 0.f};

    bf16x8 af[4], bfr[4];
#pragma unroll
    for (int mf = 0; mf < 4; ++mf)
        af[mf] = *(const bf16x8*)&As[wr * 64 + mf * 16 + lr][lk];
#pragma unroll
    for (int nf = 0; nf < 4; ++nf)
        bfr[nf] = *(const bf16x8*)&Bs[wc * 64 + nf * 16 + lr][lk];
#pragma unroll
    for (int mf = 0; mf < 4; ++mf)
#pragma unroll
        for (int nf = 0; nf < 4; ++nf)
            acc[mf][nf] = __builtin_amdgcn_mfma_f32_16x16x32_bf16(
                bfr[nf], af[mf], acc[mf][nf], 0, 0, 0);

    const int c4 = (lane >> 4) << 2;
#pragma unroll
    for (int nf = 0; nf < 4; ++nf) {
        const int col0 = bcol + wc * 64 + nf * 16 + c4;
        const f32x4 bv = *(const f32x4*)&bias[col0];
#pragma unroll
        for (int mf = 0; mf < 4; ++mf) {
            const int row = brow + wr * 64 + mf * 16 + lr;
            f32x4 v = acc[mf][nf] + bv;
#pragma unroll
            for (int rr = 0; rr < 4; ++rr) v[rr] = gelu_fast(v[rr]);
            *(unsigned short*)&C[((size_t)row * H_CONST + col0) >> 1] = pack_fp4x4(v);
        }
    }
}

// ---------------- big GEMM: R6 schedule, MX-fp4 K=128 (m153 port) --------------
// 128x128 tile, 4 waves 2x2, BK=128 fp4 -> 64-B LDS rows (8 KiB/tile, 16 KiB
// total), same 2-barrier single-buffer loop, 3 blocks/CU.
// 64-B rows = 4 x 16B slots -> R8-proven slot swizzle slot^( (row>>1)&3 )
// (both-sides: pre-swizzled global source + swizzled frag read; 2 lanes/bank
// group = conflict-free). Fragment = one b128/lane (low 4 dwords of v8i32;
// fp4 FMT=4 reads 4 regs). Scales as R12: weights 2^-5, activations 1.0.
template <bool GELU, bool OUT32>
__global__ __launch_bounds__(256, 3) void k_gemm_mx4(
    const unsigned char* __restrict__ A, const unsigned char* __restrict__ WT,
    const float* __restrict__ bias, void* __restrict__ Cout,
    int M, int N, int K) {
    __shared__ unsigned char As[128][64];   // 8 KiB
    __shared__ unsigned char Bs[128][64];   // 8 KiB

    const int lane = threadIdx.x & 63;
    const int wid  = threadIdx.x >> 6;
    const int wr = wid >> 1, wc = wid & 1;

    const int nwg_x = gridDim.x;
    const int orig = blockIdx.y * nwg_x + blockIdx.x;
    const int cpx = (nwg_x * gridDim.y) >> 3;   // nwg = 2056, %8 == 0
    const int wgid = (orig & 7) * cpx + (orig >> 3);
    const int brow = (wgid / nwg_x) * 128;
    const int bcol = (wgid % nwg_x) * 128;

    f32x4 acc[4][4];
#pragma unroll
    for (int i = 0; i < 4; ++i)
#pragma unroll
        for (int j = 0; j < 4; ++j)
            acc[i][j] = (f32x4){0.f, 0.f, 0.f, 0.f};

    // staging: per K-tile each wave covers 32 rows x 64 B = 2 loads per matrix.
    // 1-KB load: lane l -> row l>>2 (16 rows), slot l&3. Pre-swizzled global
    // source: fetch slot (l&3) ^ ((row>>1)&3) = (l&3) ^ ((l>>3)&3).
    const int KB = K >> 1;                           // 512 bytes/row
    const int srow = lane >> 2;
    const int sgrp = 16 * ((lane & 3) ^ ((lane >> 3) & 3));
    const unsigned char* Ab = A  + (size_t)(brow + wid * 32 + srow) * KB + sgrp;
    const unsigned char* Bb = WT + (size_t)(bcol + wid * 32 + srow) * KB + sgrp;
    const size_t r16 = (size_t)16 * KB;

#define STG(ko)                                                   \
    do {                                                          \
        gload_lds16(Ab + (ko),       &As[wid * 32][0]);           \
        gload_lds16(Ab + r16 + (ko), &As[wid * 32 + 16][0]);      \
        gload_lds16(Bb + (ko),       &Bs[wid * 32][0]);           \
        gload_lds16(Bb + r16 + (ko), &Bs[wid * 32 + 16][0]);      \
    } while (0)

    // fragment reads: op-row = frag*16 + (lane&15); lane's 32 k-elems = 16 B
    // at slot lane>>4, swizzled with (row>>1)&3 = ((lane&15)>>1)&3.
    const int lr = lane & 15;
    const int cb = ((lane >> 4) ^ ((lr >> 1) & 3)) << 4;

    const int nt = K >> 7;   // 8 K-tiles of 128
    STG(0);

    for (int t = 0; t < nt; ++t) {
        __syncthreads();                 // stage-t loads landed (vmcnt drain)

        const char* ab = (const char*)&As[0][0];
        const char* bb = (const char*)&Bs[0][0];
        i32x8 af[4], bfr[4];
#pragma unroll
        for (int mf = 0; mf < 4; ++mf) {
            i32x4 d = *(const i32x4*)(ab + (wr * 64 + mf * 16 + lr) * 64 + cb);
            af[mf] = (i32x8){d[0], d[1], d[2], d[3], 0, 0, 0, 0};
        }
#pragma unroll
        for (int nf = 0; nf < 4; ++nf) {
            i32x4 d = *(const i32x4*)(bb + (wc * 64 + nf * 16 + lr) * 64 + cb);
            bfr[nf] = (i32x8){d[0], d[1], d[2], d[3], 0, 0, 0, 0};
        }
        __syncthreads();                 // all waves done reading LDS (cheap)

        if (t + 1 < nt) STG((t + 1) * 64);   // next tile flies under the MFMAs

        __builtin_amdgcn_s_setprio(1);
#pragma unroll
        for (int mf = 0; mf < 4; ++mf)
#pragma unroll
            for (int nf = 0; nf < 4; ++nf)
                acc[mf][nf] = __builtin_amdgcn_mfma_scale_f32_16x16x128_f8f6f4(
                    bfr[nf], af[mf], acc[mf][nf],
                    4, 4,              // cbsz, blgp: fp4 / fp4
                    0, SC_W32,         // scale_a (weights, x32 undone)
                    0, SC_UNIT);       // scale_b (activations)
        __builtin_amdgcn_s_setprio(0);
    }
#undef STG

    // epilogue: swapped C^T frag -> lane holds 4 consecutive cols of one row
    const int c4 = (lane >> 4) << 2;
#pragma unroll
    for (int nf = 0; nf < 4; ++nf) {
        const int col0 = bcol + wc * 64 + nf * 16 + c4;
        const f32x4 bv = *(const f32x4*)&bias[col0];
#pragma unroll
        for (int mf = 0; mf < 4; ++mf) {
            const int row = brow + wr * 64 + mf * 16 + lr;
            f32x4 v = acc[mf][nf] + bv;
            if (GELU) {
#pragma unroll
                for (int rr = 0; rr < 4; ++rr) v[rr] = gelu_fast(v[rr]);
            }
            if constexpr (OUT32) {
                *(f32x4*)&((float*)Cout)[(size_t)row * N + col0] = v;
            } else {
                unsigned char* C8 = (unsigned char*)Cout;
                *(unsigned short*)&C8[((size_t)row * N + col0) >> 1] = pack_fp4x4(v);
            }
        }
    }
}

extern "C" void kernel_launch(void* const* d_in, const int* in_sizes, int n_in,
                              void* d_out, int out_size, void* d_ws, size_t ws_size,
                              hipStream_t stream) {
    const float* x  = (const float*)d_in[0];
    const float* w1 = (const float*)d_in[1];
    const float* b1 = (const float*)d_in[2];
    const float* w2 = (const float*)d_in[3];
    const float* b2 = (const float*)d_in[4];
    const float* w3 = (const float*)d_in[5];
    const float* b3 = (const float*)d_in[6];

    const int total = (out_size - B_CONST) / H_CONST;  // 32896
    float* out = (float*)d_out;
    float* out_pc = out + (size_t)total * H_CONST;

    char* ws = (char*)d_ws;
    int* valid  = (int*)ws;
    int* pc     = valid + 256;
    int* starts = pc + 256;
    int* cum    = starts + 256;
    __bf16* w1t = (__bf16*)(ws + 4096);                                 // 64 KB
    unsigned char* w2t = (unsigned char*)(w1t + (size_t)H_CONST * 32);  // 512 KB fp4
    unsigned char* w3t = w2t + (size_t)H_CONST * H_CONST / 2;           // 512 KB fp4
    unsigned char* h1  = w3t + (size_t)H_CONST * H_CONST / 2;           // total*512 B
    unsigned char* h2  = h1 + (size_t)total * H_CONST / 2;

    k_valid<<<B_CONST, 64, 0, stream>>>(x, valid);
    k_prep<<<2053, 256, 0, stream>>>(valid, pc, starts, cum, out_pc,
                                     w1, w1t, w2, w2t, w3, w3t);

    // layer 1: fused gather + K=32 bf16 GEMM, fp4 output
    dim3 g1(H_CONST / 128, total / 128);   // 8 x 257 = 2056, %8 == 0
    k_l1_fused<<<g1, dim3(256), 0, stream>>>(x, valid, cum, starts, w1t, b1, h1, total);

    // layers 2/3: MX-fp4 K=128 kernel (R6 schedule), 3 blocks/CU
    k_gemm_mx4<true,  false><<<g1, dim3(256), 0, stream>>>(h1, w2t, b2, h2, total, H_CONST, H_CONST);
    k_gemm_mx4<false, true ><<<g1, dim3(256), 0, stream>>>(h2, w3t, b3, out, total, H_CONST, H_CONST);
}